// Round 1
// baseline (5778.946 us; speedup 1.0000x reference)
//
#include <hip/hip_runtime.h>
#include <hip/hip_bf16.h>

#define H_DIM   4096
#define S_LEN   1024
#define N_HEADS 32
#define N_KV    8
#define HEAD_D  128
#define I_SZ    11008
#define N_LAYERS 2
#define EPSV    1e-5f

typedef __bf16 bf16_t;
typedef __attribute__((ext_vector_type(8))) __bf16 bf16x8;
typedef __attribute__((ext_vector_type(4))) float f32x4;

__device__ __forceinline__ unsigned bpack(float a, float b) {
  unsigned ua = __float_as_uint(a);
  ua = (ua + 0x7FFFu + ((ua >> 16) & 1u)) >> 16;
  unsigned ub = __float_as_uint(b);
  ub = (ub + 0x7FFFu + ((ub >> 16) & 1u)) >> 16;
  return ua | (ub << 16);
}
__device__ __forceinline__ bf16_t f2b(float f) {
  unsigned u = __float_as_uint(f);
  u = (u + 0x7FFFu + ((u >> 16) & 1u)) >> 16;
  unsigned short s = (unsigned short)u;
  return __builtin_bit_cast(bf16_t, s);
}
__device__ __forceinline__ float blo(unsigned u){ return __uint_as_float(u << 16); }
__device__ __forceinline__ float bhi(unsigned u){ return __uint_as_float(u & 0xFFFF0000u); }
__device__ __forceinline__ float b2f(bf16_t b){
  unsigned short s = __builtin_bit_cast(unsigned short, b);
  return __uint_as_float(((unsigned)s) << 16);
}

// ---------------- GEMM: C[M,N] = A[M,K](bf16) @ W[N,K](f32)^T -----------------
// EPI 0: outF = acc
// EPI 1: outF = resid + acc
// EPI 2: outB = bf16( silu(gate) * acc )
template<int EPI>
__global__ __launch_bounds__(256)
void gemm_kernel(const bf16_t* __restrict__ A, const float* __restrict__ W,
                 float* __restrict__ outF, bf16_t* __restrict__ outB,
                 const float* __restrict__ resid, const float* __restrict__ gate,
                 int M, int N, int K)
{
  constexpr int BK = 64;
  constexpr int LDA = BK + 8;           // 72 bf16 = 144B row stride -> 2-way banks (free)
  __shared__ bf16_t As[128 * LDA];
  __shared__ bf16_t Bs[128 * LDA];
  const int tid  = threadIdx.x;
  const int m0   = blockIdx.y * 128, n0 = blockIdx.x * 128;
  const int wave = tid >> 6, lane = tid & 63;
  const int wm   = (wave >> 1) * 64, wn = (wave & 1) * 64;
  const int lrow = lane & 15, quad = lane >> 4;
  const int srow = tid >> 1, scol = (tid & 1) * 32;

  f32x4 acc[4][4] = {};

  for (int k0 = 0; k0 < K; k0 += BK) {
    // global loads first (overlap with previous tile's compute)
    const uint4* gA = reinterpret_cast<const uint4*>(A + (size_t)(m0 + srow) * K + k0 + scol);
    uint4 a0 = gA[0], a1 = gA[1], a2 = gA[2], a3 = gA[3];
    const float4* gW = reinterpret_cast<const float4*>(W + (size_t)(n0 + srow) * K + k0 + scol);
    float4 w0 = gW[0], w1 = gW[1], w2 = gW[2], w3 = gW[3];
    float4 w4 = gW[4], w5 = gW[5], w6 = gW[6], w7 = gW[7];

    __syncthreads();   // previous compute done reading LDS
    uint4* sA = reinterpret_cast<uint4*>(&As[srow * LDA + scol]);
    sA[0] = a0; sA[1] = a1; sA[2] = a2; sA[3] = a3;
    uint4* sB = reinterpret_cast<uint4*>(&Bs[srow * LDA + scol]);
    sB[0] = make_uint4(bpack(w0.x,w0.y), bpack(w0.z,w0.w), bpack(w1.x,w1.y), bpack(w1.z,w1.w));
    sB[1] = make_uint4(bpack(w2.x,w2.y), bpack(w2.z,w2.w), bpack(w3.x,w3.y), bpack(w3.z,w3.w));
    sB[2] = make_uint4(bpack(w4.x,w4.y), bpack(w4.z,w4.w), bpack(w5.x,w5.y), bpack(w5.z,w5.w));
    sB[3] = make_uint4(bpack(w6.x,w6.y), bpack(w6.z,w6.w), bpack(w7.x,w7.y), bpack(w7.z,w7.w));
    __syncthreads();

    #pragma unroll
    for (int kk = 0; kk < BK; kk += 32) {
      bf16x8 af[4], bw[4];
      #pragma unroll
      for (int i = 0; i < 4; ++i)
        af[i] = *reinterpret_cast<const bf16x8*>(&As[(wm + i*16 + lrow) * LDA + kk + quad * 8]);
      #pragma unroll
      for (int i = 0; i < 4; ++i)
        bw[i] = *reinterpret_cast<const bf16x8*>(&Bs[(wn + i*16 + lrow) * LDA + kk + quad * 8]);
      #pragma unroll
      for (int mi = 0; mi < 4; ++mi)
        #pragma unroll
        for (int ni = 0; ni < 4; ++ni)
          acc[mi][ni] = __builtin_amdgcn_mfma_f32_16x16x32_bf16(af[mi], bw[ni], acc[mi][ni], 0, 0, 0);
    }
  }

  #pragma unroll
  for (int mi = 0; mi < 4; ++mi) {
    #pragma unroll
    for (int ni = 0; ni < 4; ++ni) {
      #pragma unroll
      for (int r = 0; r < 4; ++r) {
        int row = m0 + wm + mi*16 + quad*4 + r;
        int col = n0 + wn + ni*16 + lrow;
        size_t idx = (size_t)row * N + col;
        float v = acc[mi][ni][r];
        if (EPI == 0) {
          outF[idx] = v;
        } else if (EPI == 1) {
          outF[idx] = resid[idx] + v;
        } else {
          float g = gate[idx];
          float sg = g / (1.0f + __expf(-g));
          outB[idx] = f2b(sg * v);
        }
      }
    }
  }
}

// ---------------- RMSNorm: fp32 in -> bf16 out ----------------
__global__ __launch_bounds__(256)
void rmsnorm_kernel(const float* __restrict__ in, const float* __restrict__ w,
                    bf16_t* __restrict__ out)
{
  __shared__ float red[4];
  const int row = blockIdx.x;
  const float* xr = in + (size_t)row * H_DIM;
  float ss = 0.f;
  #pragma unroll
  for (int it = 0; it < H_DIM / 1024; ++it) {
    int c = threadIdx.x * 4 + it * 1024;
    float4 v = *reinterpret_cast<const float4*>(xr + c);
    ss += v.x*v.x + v.y*v.y + v.z*v.z + v.w*v.w;
  }
  #pragma unroll
  for (int o = 32; o; o >>= 1) ss += __shfl_down(ss, o);
  if ((threadIdx.x & 63) == 0) red[threadIdx.x >> 6] = ss;
  __syncthreads();
  float inv = rsqrtf((red[0] + red[1] + red[2] + red[3]) * (1.0f / H_DIM) + EPSV);
  #pragma unroll
  for (int it = 0; it < H_DIM / 1024; ++it) {
    int c = threadIdx.x * 4 + it * 1024;
    float4 v  = *reinterpret_cast<const float4*>(xr + c);
    float4 wv = *reinterpret_cast<const float4*>(w + c);
    uint2 p;
    p.x = bpack(v.x * inv * wv.x, v.y * inv * wv.y);
    p.y = bpack(v.z * inv * wv.z, v.w * inv * wv.w);
    *reinterpret_cast<uint2*>(out + (size_t)row * H_DIM + c) = p;
  }
}

// ---------------- RoPE Q: fp32 [S, NH*HD] -> bf16 ----------------
__global__ __launch_bounds__(256)
void rope_q_kernel(const float* __restrict__ q, const float* __restrict__ cosT,
                   const float* __restrict__ sinT, bf16_t* __restrict__ qb)
{
  int idx = blockIdx.x * 256 + threadIdx.x;    // over S*NH*HD
  int d = idx & (HEAD_D - 1);
  int s = idx >> 12;                           // / (NH*HD)
  float c  = cosT[(s << 7) + d];
  float sn = sinT[(s << 7) + d];
  float v = q[idx];
  float other = (d < 64) ? -q[idx + 64] : q[idx - 64];
  qb[idx] = f2b(v * c + other * sn);
}

// ---------------- RoPE K: fp32 [S, NKV*HD] -> bf16 ws + fp32 d_out ----------------
__global__ __launch_bounds__(256)
void rope_k_kernel(const float* __restrict__ k, const float* __restrict__ cosT,
                   const float* __restrict__ sinT, bf16_t* __restrict__ kb,
                   float* __restrict__ keys_out)   // [NKV, S, HD]
{
  int idx = blockIdx.x * 256 + threadIdx.x;    // over S*NKV*HD
  int d = idx & 127;
  int s = idx >> 10;
  int kvh = (idx >> 7) & 7;
  float c  = cosT[(s << 7) + d];
  float sn = sinT[(s << 7) + d];
  float v = k[idx];
  float other = (d < 64) ? -k[idx + 64] : k[idx - 64];
  float r = v * c + other * sn;
  kb[idx] = f2b(r);
  keys_out[(((size_t)kvh << 10) + s) * 128 + d] = r;
}

// ---------------- V copy: fp32 [S, NKV*HD] -> bf16 ws + fp32 d_out ----------------
__global__ __launch_bounds__(256)
void vcopy_kernel(const float* __restrict__ v, bf16_t* __restrict__ vb,
                  float* __restrict__ vals_out)
{
  int idx = blockIdx.x * 256 + threadIdx.x;
  int d = idx & 127;
  int s = idx >> 10;
  int kvh = (idx >> 7) & 7;
  float r = v[idx];
  vb[idx] = f2b(r);
  vals_out[(((size_t)kvh << 10) + s) * 128 + d] = r;
}

// ---------------- Attention: one block per (head, q-row), causal ----------------
__global__ __launch_bounds__(128)
void attn_kernel(const bf16_t* __restrict__ qb,   // [S, NH*HD]
                 const bf16_t* __restrict__ kb,   // [S, NKV*HD]
                 const bf16_t* __restrict__ vb,   // [S, NKV*HD]
                 bf16_t* __restrict__ attn_out)   // [S, NH*HD]
{
  __shared__ float qs[HEAD_D];
  __shared__ float sc[S_LEN];
  __shared__ float red[2];
  const int head = blockIdx.x, qrow = blockIdx.y;
  const int kvh = head >> 2;
  const int tid = threadIdx.x;
  const int nk = qrow + 1;

  qs[tid] = b2f(qb[(size_t)qrow * H_DIM + head * HEAD_D + tid]);
  __syncthreads();

  const float scale = 0.08838834764831845f;  // 1/sqrt(128)
  float lmax = -1e30f;
  for (int key = tid; key < nk; key += 128) {
    const bf16_t* kr = kb + (size_t)key * (N_KV * HEAD_D) + kvh * HEAD_D;
    float s = 0.f;
    #pragma unroll
    for (int j = 0; j < HEAD_D; j += 8) {
      uint4 u = *reinterpret_cast<const uint4*>(kr + j);
      s += qs[j+0]*blo(u.x) + qs[j+1]*bhi(u.x)
         + qs[j+2]*blo(u.y) + qs[j+3]*bhi(u.y)
         + qs[j+4]*blo(u.z) + qs[j+5]*bhi(u.z)
         + qs[j+6]*blo(u.w) + qs[j+7]*bhi(u.w);
    }
    s *= scale;
    sc[key] = s;
    lmax = fmaxf(lmax, s);
  }
  // block max
  float m = lmax;
  #pragma unroll
  for (int o = 32; o; o >>= 1) m = fmaxf(m, __shfl_down(m, o));
  if ((tid & 63) == 0) red[tid >> 6] = m;
  __syncthreads();
  float gmax = fmaxf(red[0], red[1]);
  __syncthreads();
  // exp + block sum
  float lsum = 0.f;
  for (int key = tid; key < nk; key += 128) {
    float p = __expf(sc[key] - gmax);
    sc[key] = p;
    lsum += p;
  }
  #pragma unroll
  for (int o = 32; o; o >>= 1) lsum += __shfl_down(lsum, o);
  if ((tid & 63) == 0) red[tid >> 6] = lsum;
  __syncthreads();
  float inv = 1.0f / (red[0] + red[1]);
  // O = P @ V : thread tid handles dim d=tid
  float acc = 0.f;
  for (int key = 0; key < nk; ++key) {
    acc += sc[key] * b2f(vb[(size_t)key * (N_KV * HEAD_D) + kvh * HEAD_D + tid]);
  }
  attn_out[(size_t)qrow * H_DIM + head * HEAD_D + tid] = f2b(acc * inv);
}

__global__ __launch_bounds__(256)
void copy_kernel(const float* __restrict__ src, float* __restrict__ dst)
{
  int idx = blockIdx.x * 256 + threadIdx.x;
  dst[idx] = src[idx];
}

extern "C" void kernel_launch(void* const* d_in, const int* in_sizes, int n_in,
                              void* d_out, int out_size, void* d_ws, size_t ws_size,
                              hipStream_t stream)
{
  const float* x    = (const float*)d_in[0];
  // d_in[1] attention_mask: causal by construction (implemented directly)
  // d_in[2] position_ids:   arange by construction
  const float* cosT = (const float*)d_in[3];
  const float* sinT = (const float*)d_in[4];
  const float* ln1  = (const float*)d_in[5];
  const float* ln2  = (const float*)d_in[6];
  const float* qw   = (const float*)d_in[7];
  const float* kw   = (const float*)d_in[8];
  const float* vw   = (const float*)d_in[9];
  const float* ow   = (const float*)d_in[10];
  const float* gw   = (const float*)d_in[11];
  const float* uw   = (const float*)d_in[12];
  const float* dw   = (const float*)d_in[13];
  float* out = (float*)d_out;
  char* ws = (char*)d_ws;

  // workspace layout (bytes)
  float*  h_f32    = (float*)(ws);                       // 16 MB
  bf16_t* n_bf16   = (bf16_t*)(ws + 16777216);           // 8 MB
  char*   SB       = ws + 25165824;
  float*  q_f32    = (float*)(SB);                       // 16 MB
  float*  k_f32    = (float*)(SB + 16777216);            // 4 MB
  float*  v_f32    = (float*)(SB + 20971520);            // 4 MB
  bf16_t* q_bf16   = (bf16_t*)(SB + 25165824);           // 8 MB
  bf16_t* k_bf16   = (bf16_t*)(SB + 33554432);           // 2 MB
  bf16_t* v_bf16   = (bf16_t*)(SB + 35651584);           // 2 MB
  bf16_t* at_bf16  = (bf16_t*)(SB + 37748736);           // 8 MB
  float*  gate_f32 = (float*)(SB);                       // 45 MB (reuses qkv scratch, phase-disjoint)
  bf16_t* act_bf16 = (bf16_t*)(SB + 46137344);           // 22.5 MB

  float* keys_out = out + 4194304;
  float* vals_out = out + 6291456;

  const size_t qo_stride = (size_t)H_DIM * H_DIM;          // 16.7M elems
  const size_t kv_stride = (size_t)N_KV * HEAD_D * H_DIM;  // 4.19M elems
  const size_t mlp_stride = (size_t)I_SZ * H_DIM;          // 45.1M elems

  for (int l = 0; l < N_LAYERS; ++l) {
    const float* h_in = (l == 0) ? x : h_f32;
    // attn block
    rmsnorm_kernel<<<S_LEN, 256, 0, stream>>>(h_in, ln1 + (size_t)l * H_DIM, n_bf16);
    gemm_kernel<0><<<dim3(32, 8), 256, 0, stream>>>(n_bf16, qw + l * qo_stride,
        q_f32, nullptr, nullptr, nullptr, S_LEN, H_DIM, H_DIM);
    gemm_kernel<0><<<dim3(8, 8), 256, 0, stream>>>(n_bf16, kw + l * kv_stride,
        k_f32, nullptr, nullptr, nullptr, S_LEN, N_KV * HEAD_D, H_DIM);
    gemm_kernel<0><<<dim3(8, 8), 256, 0, stream>>>(n_bf16, vw + l * kv_stride,
        v_f32, nullptr, nullptr, nullptr, S_LEN, N_KV * HEAD_D, H_DIM);
    rope_q_kernel<<<16384, 256, 0, stream>>>(q_f32, cosT, sinT, q_bf16);
    rope_k_kernel<<<4096, 256, 0, stream>>>(k_f32, cosT, sinT, k_bf16,
        keys_out + (size_t)l * N_KV * S_LEN * HEAD_D);
    vcopy_kernel<<<4096, 256, 0, stream>>>(v_f32, v_bf16,
        vals_out + (size_t)l * N_KV * S_LEN * HEAD_D);
    attn_kernel<<<dim3(N_HEADS, S_LEN), 128, 0, stream>>>(q_bf16, k_bf16, v_bf16, at_bf16);
    gemm_kernel<1><<<dim3(32, 8), 256, 0, stream>>>(at_bf16, ow + l * qo_stride,
        h_f32, nullptr, h_in, nullptr, S_LEN, H_DIM, H_DIM);
    // mlp block
    rmsnorm_kernel<<<S_LEN, 256, 0, stream>>>(h_f32, ln2 + (size_t)l * H_DIM, n_bf16);
    gemm_kernel<0><<<dim3(86, 8), 256, 0, stream>>>(n_bf16, gw + l * mlp_stride,
        gate_f32, nullptr, nullptr, nullptr, S_LEN, I_SZ, H_DIM);
    gemm_kernel<2><<<dim3(86, 8), 256, 0, stream>>>(n_bf16, uw + l * mlp_stride,
        nullptr, act_bf16, nullptr, gate_f32, S_LEN, I_SZ, H_DIM);
    gemm_kernel<1><<<dim3(32, 8), 256, 0, stream>>>(act_bf16, dw + l * mlp_stride,
        h_f32, nullptr, h_f32, nullptr, S_LEN, H_DIM, I_SZ);
  }
  copy_kernel<<<16384, 256, 0, stream>>>(h_f32, out);
}